// Round 7
// baseline (499.145 us; speedup 1.0000x reference)
//
#include <hip/hip_runtime.h>
#include <math.h>

#define N_NODES 100000
#define N_EDGES 1600000
#define NB_SCAN 391   // ceil(N_NODES/256)
#define CHUNK 4096
#define NCHA 391      // ceil(N_EDGES/CHUNK)
#define NBUK 256      // coarse dst buckets
#define DPB 391       // dsts per bucket (256*391 = 100096 >= 100000)
#define BSTRIDE 7168  // per-bucket capacity (mean 6250, sigma ~79)
#define NT 4          // src tiles
#define TILE_N 25000  // srcs per tile (3.2 MB bf16, fits 4 MB XCD L2)
#define NPB 64        // nodes per pull block (32 KB LDS accumulators)
#define NBLK_PULL 1563

typedef __attribute__((ext_vector_type(8))) short bf16x8;
typedef __attribute__((ext_vector_type(4))) float f32x4;

__device__ __forceinline__ unsigned short f2bf(float f) {
    union { float f; unsigned u; } v; v.f = f;
    unsigned r = v.u + 0x7FFF + ((v.u >> 16) & 1);  // round-nearest-even
    return (unsigned short)(r >> 16);
}
__device__ __forceinline__ float bf2f(unsigned short b) {
    union { unsigned u; float f; } v; v.u = ((unsigned)b) << 16;
    return v.f;
}

// ---------------------------------------------------------------------------
// f32 -> bf16 row copy of x (for the gather path).
// ---------------------------------------------------------------------------
__global__ void x2bf16_kernel(const float* __restrict__ x,
                              unsigned short* __restrict__ xb) {
    int i = blockIdx.x * 256 + threadIdx.x;
    if (i >= N_NODES * 16) return;
    float4 v = reinterpret_cast<const float4*>(x)[i];
    ushort4 o;
    o.x = f2bf(v.x); o.y = f2bf(v.y); o.z = f2bf(v.z); o.w = f2bf(v.w);
    reinterpret_cast<ushort4*>(xb)[i] = o;
}

// ---------------------------------------------------------------------------
// Weight transpose+cast: Wt[c][k] = {W[0],W[1],root}[k][c], bf16; pad rows 0.
// ---------------------------------------------------------------------------
__global__ void wt_kernel(const float* __restrict__ W, const float* __restrict__ root,
                          unsigned short* __restrict__ Wt, int COUT, int total) {
    int i = blockIdx.x * 256 + threadIdx.x;
    if (i >= total) return;
    int c = i / 192;
    int k = i - c * 192;
    float v = 0.0f;
    if (c < COUT)
        v = (k < 128) ? W[(k >> 6) * 64 * COUT + (k & 63) * COUT + c]
                      : root[(k - 128) * COUT + c];
    Wt[i] = f2bf(v);
}

// ---------------------------------------------------------------------------
// Phase A: bin edges into 256 coarse dst-buckets with LDS compaction, so all
// global writes are contiguous runs. Record: {src, u16<<16 | dst_local(10b)}.
// ---------------------------------------------------------------------------
__global__ __launch_bounds__(256) void bin_edges(const int* __restrict__ ei,
                                                 const float* __restrict__ ea,
                                                 int* __restrict__ bucket_cur,
                                                 int2* __restrict__ binned) {
    __shared__ int hist[NBUK];
    __shared__ int lbase[NBUK];
    __shared__ int lcur[NBUK];
    __shared__ int gbase[NBUK];
    __shared__ int2 stage[CHUNK];
    __shared__ unsigned char sbkt[CHUNK];
    int tid = threadIdx.x;
    int e0 = blockIdx.x * CHUNK;
    int nval = min(CHUNK, N_EDGES - e0);

    if (tid < NBUK) hist[tid] = 0;
    __syncthreads();
    for (int j = tid; j < nval; j += 256)
        atomicAdd(&hist[ei[N_EDGES + e0 + j] / DPB], 1);
    __syncthreads();
    if (tid < NBUK) lbase[tid] = hist[tid];
    __syncthreads();
    for (int off = 1; off < NBUK; off <<= 1) {
        int v = (tid < NBUK && tid >= off) ? lbase[tid - off] : 0;
        __syncthreads();
        if (tid < NBUK) lbase[tid] += v;
        __syncthreads();
    }
    if (tid < NBUK) {
        int ex = lbase[tid] - hist[tid];  // exclusive
        lbase[tid] = ex;
        lcur[tid]  = ex;
        gbase[tid] = atomicAdd(&bucket_cur[tid], hist[tid]);
    }
    __syncthreads();
    for (int j = tid; j < nval; j += 256) {
        int e = e0 + j;
        int d = ei[N_EDGES + e];
        int b = d / DPB;
        int dl = d - b * DPB;
        float u = ea[e];
        int uq = min((int)(u * 65536.0f + 0.5f), 65535);
        int pos = atomicAdd(&lcur[b], 1);
        stage[pos] = make_int2(ei[e], (uq << 16) | dl);
        sbkt[pos] = (unsigned char)b;
    }
    __syncthreads();
    for (int j = tid; j < nval; j += 256) {
        int b = sbkt[j];
        int gp = gbase[b] + (j - lbase[b]);
        if (gp < BSTRIDE)
            binned[(size_t)b * BSTRIDE + gp] = stage[j];
    }
}

// ---------------------------------------------------------------------------
// Phase B: per-bucket counting sort over key = dst_local*4 + src_tile.
// Emits rowptr2[(d*4+t)] (monotone over all 400384 keys; deg and sub-list
// bounds both derive from it) and dst/tile-sorted rec with coalesced writes.
// ---------------------------------------------------------------------------
__global__ __launch_bounds__(512) void bucket_sort(const int* __restrict__ bucket_cur,
                                                   const int2* __restrict__ binned,
                                                   int2* __restrict__ rec,
                                                   int* __restrict__ rowptr2) {
    __shared__ int keycnt[1600];
    __shared__ int tsum[512];
    __shared__ int2 stage[BSTRIDE];
    int tid = threadIdx.x;
    int b = blockIdx.x;

    // global base of this bucket = exclusive prefix of bucket sizes
    tsum[tid] = (tid < NBUK) ? bucket_cur[tid] : 0;
    __syncthreads();
    for (int off = 1; off < 512; off <<= 1) {
        int v = (tid >= off) ? tsum[tid - off] : 0;
        __syncthreads();
        tsum[tid] += v;
        __syncthreads();
    }
    int base = (b == 0) ? 0 : tsum[b - 1];
    int m = min(bucket_cur[b], BSTRIDE);
    __syncthreads();

    for (int k = tid; k < 1600; k += 512) keycnt[k] = 0;
    __syncthreads();
    const int2* bin = binned + (size_t)b * BSTRIDE;
    for (int j = tid; j < m; j += 512) {
        int2 r = bin[j];
        int key = ((r.y & 1023) << 2) + (unsigned)r.x / TILE_N;
        atomicAdd(&keycnt[key], 1);
    }
    __syncthreads();
    int k0 = tid << 2;
    int c0 = 0, c1 = 0, c2 = 0, c3 = 0;
    if (tid < DPB) {
        c0 = keycnt[k0]; c1 = keycnt[k0 + 1];
        c2 = keycnt[k0 + 2]; c3 = keycnt[k0 + 3];
    }
    int s = c0 + c1 + c2 + c3;
    tsum[tid] = s;
    __syncthreads();
    for (int off = 1; off < 512; off <<= 1) {
        int v = (tid >= off) ? tsum[tid - off] : 0;
        __syncthreads();
        tsum[tid] += v;
        __syncthreads();
    }
    if (tid < DPB) {
        int p = tsum[tid] - s;  // exclusive over keys
        int gk = b * (DPB * 4) + k0;
        rowptr2[gk]     = base + p; keycnt[k0]     = p; p += c0;
        rowptr2[gk + 1] = base + p; keycnt[k0 + 1] = p; p += c1;
        rowptr2[gk + 2] = base + p; keycnt[k0 + 2] = p; p += c2;
        rowptr2[gk + 3] = base + p; keycnt[k0 + 3] = p; p += c3;
    }
    __syncthreads();
    for (int j = tid; j < m; j += 512) {
        int2 r = bin[j];
        int key = ((r.y & 1023) << 2) + (unsigned)r.x / TILE_N;
        float u = ((unsigned)r.y >> 16) * (1.0f / 65536.0f);
        int pos = atomicAdd(&keycnt[key], 1);
        if (pos < BSTRIDE) stage[pos] = make_int2(r.x, __float_as_int(u));
    }
    __syncthreads();
    for (int j = tid; j < m; j += 512)
        rec[base + j] = stage[j];
}

// ---------------------------------------------------------------------------
// Src-tiled pull aggregation. Block = 64 nodes, 32 KB f32 LDS accumulators
// (exactly 5 blocks/CU). Outer loop over 4 src-tiles: resident blocks sweep
// tiles in rough lockstep, so during phase t each XCD's L2 holds tile t
// (3.2 MB) and the random row gathers become L2 hits.
// Wave owns nodes wave,wave+4,...; 16 lanes/edge (128 B row), 4 edges in
// flight, shfl_xor reduce, non-atomic LDS accumulate.
// ---------------------------------------------------------------------------
__global__ __launch_bounds__(256) void pull_agg_tiled(
        const int* __restrict__ rowptr2, const int2* __restrict__ rec,
        const unsigned short* __restrict__ featb,
        unsigned short* __restrict__ s01b) {
    __shared__ float accL[NPB][128];
    int tid = threadIdx.x;
    int nb = blockIdx.x * NPB;
    {
        float4* a4 = (float4*)&accL[0][0];
        for (int i = tid; i < NPB * 32; i += 256)
            a4[i] = make_float4(0.f, 0.f, 0.f, 0.f);
    }
    __syncthreads();
    int wave = tid >> 6, lane = tid & 63;
    int fg = lane & 15, eg = lane >> 4;
    const ushort4* f4 = reinterpret_cast<const ushort4*>(featb);

    for (int t = 0; t < NT; ++t) {
        for (int nl = wave; nl < NPB; nl += 4) {
            int n = nb + nl;
            if (n >= N_NODES) break;
            int a = rowptr2[n * 4 + t];
            int e = rowptr2[n * 4 + t + 1];
            if (a >= e) continue;
            float4 a0 = make_float4(0.f, 0.f, 0.f, 0.f);
            float4 a1 = make_float4(0.f, 0.f, 0.f, 0.f);
            for (int i = a + eg; i < e; i += 4) {
                int2 r  = rec[i];
                float u = __int_as_float(r.y);
                ushort4 vb = f4[(size_t)r.x * 16 + fg];
                float vx = bf2f(vb.x), vy = bf2f(vb.y), vz = bf2f(vb.z), vw = bf2f(vb.w);
                float w0 = 1.0f - u;
                a0.x = fmaf(w0, vx, a0.x); a0.y = fmaf(w0, vy, a0.y);
                a0.z = fmaf(w0, vz, a0.z); a0.w = fmaf(w0, vw, a0.w);
                a1.x = fmaf(u, vx, a1.x);  a1.y = fmaf(u, vy, a1.y);
                a1.z = fmaf(u, vz, a1.z);  a1.w = fmaf(u, vw, a1.w);
            }
#define RED4(A)                                             \
    A.x += __shfl_xor(A.x, 16); A.y += __shfl_xor(A.y, 16); \
    A.z += __shfl_xor(A.z, 16); A.w += __shfl_xor(A.w, 16); \
    A.x += __shfl_xor(A.x, 32); A.y += __shfl_xor(A.y, 32); \
    A.z += __shfl_xor(A.z, 32); A.w += __shfl_xor(A.w, 32);
            RED4(a0);
            RED4(a1);
#undef RED4
            if (eg == 0) {
                accL[nl][4 * fg + 0] += a0.x;
                accL[nl][4 * fg + 1] += a0.y;
                accL[nl][4 * fg + 2] += a0.z;
                accL[nl][4 * fg + 3] += a0.w;
            } else if (eg == 1) {
                accL[nl][64 + 4 * fg + 0] += a1.x;
                accL[nl][64 + 4 * fg + 1] += a1.y;
                accL[nl][64 + 4 * fg + 2] += a1.z;
                accL[nl][64 + 4 * fg + 3] += a1.w;
            }
        }
    }
    __syncthreads();
    // mean + bf16 writeout, coalesced
    for (int v = tid; v < NPB * 32; v += 256) {
        int nl = v >> 5, q = v & 31;
        int n = nb + nl;
        if (n >= N_NODES) continue;
        int deg = rowptr2[n * 4 + 4] - rowptr2[n * 4];
        float dinv = 1.0f / fmaxf((float)deg, 1.0f);
        ushort4 o;
        o.x = f2bf(accL[nl][4 * q + 0] * dinv);
        o.y = f2bf(accL[nl][4 * q + 1] * dinv);
        o.z = f2bf(accL[nl][4 * q + 2] * dinv);
        o.w = f2bf(accL[nl][4 * q + 3] * dinv);
        *reinterpret_cast<ushort4*>(s01b + (size_t)n * 128 + 4 * q) = o;
    }
}

// ---------------------------------------------------------------------------
// MFMA node transform (per block 256 nodes; wave owns 64). K=192 in 6 steps.
// D = Wt-frag x z-frag = C^T: lane holds node = base+(lane&15), channels
// ct*16 + (lane>>4)*4 + reg. ACT=1: ELU->bf16. ACT=2: log_softmax->f32.
// ---------------------------------------------------------------------------
template<int COUT, int CT, int ACT>
__global__ __launch_bounds__(256) void gemm_mfma(
        const unsigned short* __restrict__ s01b,
        const unsigned short* __restrict__ featb,
        const unsigned short* __restrict__ Wt,
        const float* __restrict__ bias, void* __restrict__ outv) {
    int lane = threadIdx.x & 63;
    int wave = threadIdx.x >> 6;
    int l15  = lane & 15;
    int g    = lane >> 4;
    int nodebase = blockIdx.x * 256 + wave * 64;

    f32x4 acc[4][CT];
#pragma unroll
    for (int rt = 0; rt < 4; ++rt)
#pragma unroll
        for (int ct = 0; ct < CT; ++ct) acc[rt][ct] = (f32x4){0.f, 0.f, 0.f, 0.f};

#pragma unroll
    for (int ks = 0; ks < 6; ++ks) {
        int kk = ks * 32 + g * 8;
        bf16x8 zfrag[4];
#pragma unroll
        for (int rt = 0; rt < 4; ++rt) {
            int n = nodebase + rt * 16 + l15;
            if (n >= N_NODES) n = N_NODES - 1;
            const unsigned short* p = (kk < 128)
                ? (s01b + (size_t)n * 128 + kk)
                : (featb + (size_t)n * 64 + (kk - 128));
            zfrag[rt] = *reinterpret_cast<const bf16x8*>(p);
        }
        bf16x8 wfrag[CT];
#pragma unroll
        for (int ct = 0; ct < CT; ++ct)
            wfrag[ct] = *reinterpret_cast<const bf16x8*>(Wt + (size_t)(ct * 16 + l15) * 192 + kk);
#pragma unroll
        for (int rt = 0; rt < 4; ++rt)
#pragma unroll
            for (int ct = 0; ct < CT; ++ct)
                acc[rt][ct] = __builtin_amdgcn_mfma_f32_16x16x32_bf16(
                    wfrag[ct], zfrag[rt], acc[rt][ct], 0, 0, 0);
    }

    f32x4 bv[CT];
#pragma unroll
    for (int ct = 0; ct < CT; ++ct) {
        int base = ct * 16 + g * 4;
        if (base + 4 <= COUT) {
            float4 b = *reinterpret_cast<const float4*>(bias + base);
            bv[ct] = (f32x4){b.x, b.y, b.z, b.w};
        } else {
            bv[ct] = (f32x4){0.f, 0.f, 0.f, 0.f};
        }
    }

    if (ACT == 1) {
        unsigned short* out = (unsigned short*)outv;
#pragma unroll
        for (int rt = 0; rt < 4; ++rt) {
            int n = nodebase + rt * 16 + l15;
            if (n >= N_NODES) continue;
#pragma unroll
            for (int ct = 0; ct < CT; ++ct) {
                f32x4 v = acc[rt][ct] + bv[ct];
                ushort4 o;
                float e;
                e = v[0]; o.x = f2bf(e > 0.f ? e : expm1f(e));
                e = v[1]; o.y = f2bf(e > 0.f ? e : expm1f(e));
                e = v[2]; o.z = f2bf(e > 0.f ? e : expm1f(e));
                e = v[3]; o.w = f2bf(e > 0.f ? e : expm1f(e));
                *reinterpret_cast<ushort4*>(out + (size_t)n * 64 + ct * 16 + g * 4) = o;
            }
        }
    } else {
        float* out = (float*)outv;
#pragma unroll
        for (int rt = 0; rt < 4; ++rt) {
            int n = nodebase + rt * 16 + l15;
            float v[CT * 4];
            float m = -3.4e38f;
#pragma unroll
            for (int ct = 0; ct < CT; ++ct)
#pragma unroll
                for (int r = 0; r < 4; ++r) {
                    int ch = ct * 16 + g * 4 + r;
                    float t = acc[rt][ct][r] + bv[ct][r];
                    v[ct * 4 + r] = t;
                    if (ch < COUT) m = fmaxf(m, t);
                }
            m = fmaxf(m, __shfl_xor(m, 16));
            m = fmaxf(m, __shfl_xor(m, 32));
            float s = 0.0f;
#pragma unroll
            for (int ct = 0; ct < CT; ++ct)
#pragma unroll
                for (int r = 0; r < 4; ++r) {
                    int ch = ct * 16 + g * 4 + r;
                    if (ch < COUT) s += expf(v[ct * 4 + r] - m);
                }
            s += __shfl_xor(s, 16);
            s += __shfl_xor(s, 32);
            float lse = m + logf(s);
            if (n >= N_NODES) continue;
#pragma unroll
            for (int ct = 0; ct < CT; ++ct) {
                int base = ct * 16 + g * 4;
                if (base + 4 <= COUT) {
                    float4 o;
                    o.x = v[ct * 4 + 0] - lse;
                    o.y = v[ct * 4 + 1] - lse;
                    o.z = v[ct * 4 + 2] - lse;
                    o.w = v[ct * 4 + 3] - lse;
                    *reinterpret_cast<float4*>(out + (size_t)n * COUT + base) = o;
                }
            }
        }
    }
}

extern "C" void kernel_launch(void* const* d_in, const int* in_sizes, int n_in,
                              void* d_out, int out_size, void* d_ws, size_t ws_size,
                              hipStream_t stream) {
    const float* x     = (const float*)d_in[0];
    const int*   ei    = (const int*)d_in[1];
    const float* ea    = (const float*)d_in[2];
    const float* W1    = (const float*)d_in[3];
    const float* root1 = (const float*)d_in[4];
    const float* b1    = (const float*)d_in[5];
    const float* W2    = (const float*)d_in[6];
    const float* root2 = (const float*)d_in[7];
    const float* b2    = (const float*)d_in[8];
    float* out = (float*)d_out;

    // workspace layout
    char* p = (char*)d_ws;
    int*   bucket_cur = (int*)p;            p += 512 * 4;
    int2*  binned  = (int2*)p;              p += (size_t)NBUK * BSTRIDE * 8;
    int2*  rec     = (int2*)p;              p += (size_t)N_EDGES * 8;
    int*   rowptr2 = (int*)p;               p += (size_t)NBUK * DPB * 4 * 4;
    unsigned short* s01b = (unsigned short*)p;  p += (size_t)N_NODES * 128 * 2;
    unsigned short* xb   = (unsigned short*)p;  p += (size_t)N_NODES * 64 * 2;
    unsigned short* hprb = (unsigned short*)p;  p += (size_t)N_NODES * 64 * 2;
    unsigned short* Wt1  = (unsigned short*)p;  p += (size_t)64 * 192 * 2;
    unsigned short* Wt2  = (unsigned short*)p;  p += (size_t)48 * 192 * 2;

    // ---- prep ----
    x2bf16_kernel<<<(N_NODES * 16) / 256, 256, 0, stream>>>(x, xb);
    wt_kernel<<<48, 256, 0, stream>>>(W1, root1, Wt1, 64, 64 * 192);
    wt_kernel<<<36, 256, 0, stream>>>(W2, root2, Wt2, 40, 48 * 192);
    hipMemsetAsync(bucket_cur, 0, 512 * 4, stream);

    // ---- CSR build: 2-phase counting sort, key = dst*4 + src_tile ----
    bin_edges<<<NCHA, 256, 0, stream>>>(ei, ea, bucket_cur, binned);
    bucket_sort<<<NBUK, 512, 0, stream>>>(bucket_cur, binned, rec, rowptr2);

    // ---- layer 1 ----
    pull_agg_tiled<<<NBLK_PULL, 256, 0, stream>>>(rowptr2, rec, xb, s01b);
    gemm_mfma<64, 4, 1><<<NB_SCAN, 256, 0, stream>>>(s01b, xb, Wt1, b1, hprb);

    // ---- layer 2 ----
    pull_agg_tiled<<<NBLK_PULL, 256, 0, stream>>>(rowptr2, rec, hprb, s01b);
    gemm_mfma<40, 3, 2><<<NB_SCAN, 256, 0, stream>>>(s01b, hprb, Wt2, b2, out);
}

// Round 8
// 202.964 us; speedup vs baseline: 2.4593x; 2.4593x over previous
//
#include <hip/hip_runtime.h>
#include <math.h>

#define N_NODES 100000
#define N_EDGES 1600000
#define NB_SCAN 391   // ceil(N_NODES/256)
#define CHUNK 4096
#define NCHA 391      // ceil(N_EDGES/CHUNK)
#define NBUK 256      // coarse dst buckets
#define DPB 391       // dsts per bucket (256*391 = 100096 >= 100000)
#define BSTRIDE 7168  // per-bucket capacity (mean 6250, sigma ~79)

typedef __attribute__((ext_vector_type(8))) short bf16x8;
typedef __attribute__((ext_vector_type(4))) float f32x4;

__device__ __forceinline__ unsigned short f2bf(float f) {
    union { float f; unsigned u; } v; v.f = f;
    unsigned r = v.u + 0x7FFF + ((v.u >> 16) & 1);  // round-nearest-even
    return (unsigned short)(r >> 16);
}
__device__ __forceinline__ float bf2f(unsigned short b) {
    union { unsigned u; float f; } v; v.u = ((unsigned)b) << 16;
    return v.f;
}

// ---------------------------------------------------------------------------
// f32 -> bf16 row copy of x (for the gather path).
// ---------------------------------------------------------------------------
__global__ void x2bf16_kernel(const float* __restrict__ x,
                              unsigned short* __restrict__ xb) {
    int i = blockIdx.x * 256 + threadIdx.x;
    if (i >= N_NODES * 16) return;
    float4 v = reinterpret_cast<const float4*>(x)[i];
    ushort4 o;
    o.x = f2bf(v.x); o.y = f2bf(v.y); o.z = f2bf(v.z); o.w = f2bf(v.w);
    reinterpret_cast<ushort4*>(xb)[i] = o;
}

// ---------------------------------------------------------------------------
// Weight transpose+cast: Wt[c][k] = {W[0],W[1],root}[k][c], bf16; pad rows 0.
// ---------------------------------------------------------------------------
__global__ void wt_kernel(const float* __restrict__ W, const float* __restrict__ root,
                          unsigned short* __restrict__ Wt, int COUT, int total) {
    int i = blockIdx.x * 256 + threadIdx.x;
    if (i >= total) return;
    int c = i / 192;
    int k = i - c * 192;
    float v = 0.0f;
    if (c < COUT)
        v = (k < 128) ? W[(k >> 6) * 64 * COUT + (k & 63) * COUT + c]
                      : root[(k - 128) * COUT + c];
    Wt[i] = f2bf(v);
}

// ---------------------------------------------------------------------------
// Phase A: bin edges into 256 coarse dst-buckets with LDS compaction, so all
// global writes are contiguous runs. Record: {src, u16<<16 | dst_local(10b)}.
// ---------------------------------------------------------------------------
__global__ __launch_bounds__(256) void bin_edges(const int* __restrict__ ei,
                                                 const float* __restrict__ ea,
                                                 int* __restrict__ bucket_cur,
                                                 int2* __restrict__ binned) {
    __shared__ int hist[NBUK];
    __shared__ int lbase[NBUK];
    __shared__ int lcur[NBUK];
    __shared__ int gbase[NBUK];
    __shared__ int2 stage[CHUNK];
    __shared__ unsigned char sbkt[CHUNK];
    int tid = threadIdx.x;
    int e0 = blockIdx.x * CHUNK;
    int nval = min(CHUNK, N_EDGES - e0);

    if (tid < NBUK) hist[tid] = 0;
    __syncthreads();
    for (int j = tid; j < nval; j += 256)
        atomicAdd(&hist[ei[N_EDGES + e0 + j] / DPB], 1);
    __syncthreads();
    if (tid < NBUK) lbase[tid] = hist[tid];
    __syncthreads();
    for (int off = 1; off < NBUK; off <<= 1) {
        int v = (tid < NBUK && tid >= off) ? lbase[tid - off] : 0;
        __syncthreads();
        if (tid < NBUK) lbase[tid] += v;
        __syncthreads();
    }
    if (tid < NBUK) {
        int ex = lbase[tid] - hist[tid];  // exclusive
        lbase[tid] = ex;
        lcur[tid]  = ex;
        gbase[tid] = atomicAdd(&bucket_cur[tid], hist[tid]);
    }
    __syncthreads();
    for (int j = tid; j < nval; j += 256) {
        int e = e0 + j;
        int d = ei[N_EDGES + e];
        int b = d / DPB;
        int dl = d - b * DPB;
        float u = ea[e];
        int uq = min((int)(u * 65536.0f + 0.5f), 65535);
        int pos = atomicAdd(&lcur[b], 1);
        stage[pos] = make_int2(ei[e], (uq << 16) | dl);
        sbkt[pos] = (unsigned char)b;
    }
    __syncthreads();
    for (int j = tid; j < nval; j += 256) {
        int b = sbkt[j];
        int gp = gbase[b] + (j - lbase[b]);
        if (gp < BSTRIDE)
            binned[(size_t)b * BSTRIDE + gp] = stage[j];
    }
}

// ---------------------------------------------------------------------------
// Phase B: per-bucket counting sort in LDS. Emits rowptr/cnt (global CSR) and
// dst-sorted rec = {src, u(f32)} with fully coalesced writes.
// ---------------------------------------------------------------------------
__global__ __launch_bounds__(512) void bucket_sort(const int* __restrict__ bucket_cur,
                                                   const int2* __restrict__ binned,
                                                   int2* __restrict__ rec,
                                                   int* __restrict__ rowptr,
                                                   int* __restrict__ cnt_g) {
    __shared__ int cntA[512];
    __shared__ int cntB[512];
    __shared__ int2 stage[BSTRIDE];
    int tid = threadIdx.x;
    int b = blockIdx.x;

    // scan bucket sizes for this bucket's global base
    cntA[tid] = (tid < NBUK) ? bucket_cur[tid] : 0;
    __syncthreads();
    cntB[tid] = cntA[tid];
    __syncthreads();
    for (int off = 1; off < 512; off <<= 1) {
        int v = (tid >= off) ? cntB[tid - off] : 0;
        __syncthreads();
        cntB[tid] += v;
        __syncthreads();
    }
    int base = (b == 0) ? 0 : cntB[b - 1];
    int m = min(cntA[b], BSTRIDE);
    __syncthreads();

    // per-dst histogram over this bucket's 391 dsts
    cntA[tid] = 0;
    __syncthreads();
    const int2* bin = binned + (size_t)b * BSTRIDE;
    for (int j = tid; j < m; j += 512)
        atomicAdd(&cntA[bin[j].y & 1023], 1);
    __syncthreads();
    cntB[tid] = cntA[tid];
    __syncthreads();
    for (int off = 1; off < 512; off <<= 1) {
        int v = (tid >= off) ? cntB[tid - off] : 0;
        __syncthreads();
        cntB[tid] += v;
        __syncthreads();
    }
    // exclusive offsets; emit CSR; init cursors
    {
        int ex = cntB[tid] - cntA[tid];
        int d = b * DPB + tid;
        if (tid < DPB && d < N_NODES) {
            rowptr[d] = base + ex;
            cnt_g[d]  = cntA[tid];
        }
        __syncthreads();
        cntB[tid] = ex;
    }
    __syncthreads();
    // place sorted into LDS
    for (int j = tid; j < m; j += 512) {
        int2 r = bin[j];
        int dl = r.y & 1023;
        float u = ((unsigned)r.y >> 16) * (1.0f / 65536.0f);
        int pos = atomicAdd(&cntB[dl], 1);
        if (pos < BSTRIDE) stage[pos] = make_int2(r.x, __float_as_int(u));
    }
    __syncthreads();
    // coalesced stream-out
    for (int j = tid; j < m; j += 512)
        rec[base + j] = stage[j];
}

// ---------------------------------------------------------------------------
// Pull aggregation: one wave per node; 8 lanes per edge (bf16x8 = 16B each,
// 8 lanes cover the 128B row), 8 edges in flight, rec prefetch, 3-step
// shfl_xor cross-group reduce. Output bf16.
// ---------------------------------------------------------------------------
__global__ __launch_bounds__(256) void pull_agg(
        const int* __restrict__ rowptr, const int* __restrict__ cnt,
        const int2* __restrict__ rec, const unsigned short* __restrict__ featb,
        unsigned short* __restrict__ s01b) {
    int wid  = (blockIdx.x * 256 + threadIdx.x) >> 6;
    int lane = threadIdx.x & 63;
    if (wid >= N_NODES) return;
    int fg = lane & 7;    // 16B chunk (8 bf16) within the 128B row
    int eg = lane >> 3;   // edge subgroup 0..7
    int start = rowptr[wid];
    int deg   = cnt[wid];
    int end   = start + deg;
    const bf16x8* f8 = reinterpret_cast<const bf16x8*>(featb);
    float a0[8], a1[8];
#pragma unroll
    for (int k = 0; k < 8; ++k) { a0[k] = 0.0f; a1[k] = 0.0f; }

    int i = start + eg;
    if (i < end) {
        int2 r = rec[i];
        for (; i < end; i += 8) {
            int inext = min(i + 8, end - 1);
            int2 rn = rec[inext];                 // prefetch next record
            float u  = __int_as_float(r.y);
            bf16x8 vb = f8[(size_t)r.x * 8 + fg]; // 16B random gather
            float w0 = 1.0f - u;
#pragma unroll
            for (int k = 0; k < 8; ++k) {
                float v = bf2f((unsigned short)vb[k]);
                a0[k] = fmaf(w0, v, a0[k]);
                a1[k] = fmaf(u, v, a1[k]);
            }
            r = rn;
        }
    }
    // reduce across the 8 edge subgroups (xor 8, 16, 32)
#pragma unroll
    for (int k = 0; k < 8; ++k) {
        a0[k] += __shfl_xor(a0[k], 8);
        a0[k] += __shfl_xor(a0[k], 16);
        a0[k] += __shfl_xor(a0[k], 32);
        a1[k] += __shfl_xor(a1[k], 8);
        a1[k] += __shfl_xor(a1[k], 16);
        a1[k] += __shfl_xor(a1[k], 32);
    }
    float dinv = 1.0f / fmaxf((float)deg, 1.0f);
    if (eg == 0) {
        bf16x8 o;
#pragma unroll
        for (int k = 0; k < 8; ++k) o[k] = (short)f2bf(a0[k] * dinv);
        *reinterpret_cast<bf16x8*>(s01b + (size_t)wid * 128 + fg * 8) = o;
    } else if (eg == 1) {
        bf16x8 o;
#pragma unroll
        for (int k = 0; k < 8; ++k) o[k] = (short)f2bf(a1[k] * dinv);
        *reinterpret_cast<bf16x8*>(s01b + (size_t)wid * 128 + 64 + fg * 8) = o;
    }
}

// ---------------------------------------------------------------------------
// MFMA node transform (per block 256 nodes; wave owns 64). K=192 in 6 steps.
// D = Wt-frag x z-frag = C^T: lane holds node = base+(lane&15), channels
// ct*16 + (lane>>4)*4 + reg. ACT=1: ELU->bf16. ACT=2: log_softmax->f32.
// ---------------------------------------------------------------------------
template<int COUT, int CT, int ACT>
__global__ __launch_bounds__(256) void gemm_mfma(
        const unsigned short* __restrict__ s01b,
        const unsigned short* __restrict__ featb,
        const unsigned short* __restrict__ Wt,
        const float* __restrict__ bias, void* __restrict__ outv) {
    int lane = threadIdx.x & 63;
    int wave = threadIdx.x >> 6;
    int l15  = lane & 15;
    int g    = lane >> 4;
    int nodebase = blockIdx.x * 256 + wave * 64;

    f32x4 acc[4][CT];
#pragma unroll
    for (int rt = 0; rt < 4; ++rt)
#pragma unroll
        for (int ct = 0; ct < CT; ++ct) acc[rt][ct] = (f32x4){0.f, 0.f, 0.f, 0.f};

#pragma unroll
    for (int ks = 0; ks < 6; ++ks) {
        int kk = ks * 32 + g * 8;
        bf16x8 zfrag[4];
#pragma unroll
        for (int rt = 0; rt < 4; ++rt) {
            int n = nodebase + rt * 16 + l15;
            if (n >= N_NODES) n = N_NODES - 1;
            const unsigned short* p = (kk < 128)
                ? (s01b + (size_t)n * 128 + kk)
                : (featb + (size_t)n * 64 + (kk - 128));
            zfrag[rt] = *reinterpret_cast<const bf16x8*>(p);
        }
        bf16x8 wfrag[CT];
#pragma unroll
        for (int ct = 0; ct < CT; ++ct)
            wfrag[ct] = *reinterpret_cast<const bf16x8*>(Wt + (size_t)(ct * 16 + l15) * 192 + kk);
#pragma unroll
        for (int rt = 0; rt < 4; ++rt)
#pragma unroll
            for (int ct = 0; ct < CT; ++ct)
                acc[rt][ct] = __builtin_amdgcn_mfma_f32_16x16x32_bf16(
                    wfrag[ct], zfrag[rt], acc[rt][ct], 0, 0, 0);
    }

    f32x4 bv[CT];
#pragma unroll
    for (int ct = 0; ct < CT; ++ct) {
        int base = ct * 16 + g * 4;
        if (base + 4 <= COUT) {
            float4 b = *reinterpret_cast<const float4*>(bias + base);
            bv[ct] = (f32x4){b.x, b.y, b.z, b.w};
        } else {
            bv[ct] = (f32x4){0.f, 0.f, 0.f, 0.f};
        }
    }

    if (ACT == 1) {
        unsigned short* out = (unsigned short*)outv;
#pragma unroll
        for (int rt = 0; rt < 4; ++rt) {
            int n = nodebase + rt * 16 + l15;
            if (n >= N_NODES) continue;
#pragma unroll
            for (int ct = 0; ct < CT; ++ct) {
                f32x4 v = acc[rt][ct] + bv[ct];
                ushort4 o;
                float e;
                e = v[0]; o.x = f2bf(e > 0.f ? e : expm1f(e));
                e = v[1]; o.y = f2bf(e > 0.f ? e : expm1f(e));
                e = v[2]; o.z = f2bf(e > 0.f ? e : expm1f(e));
                e = v[3]; o.w = f2bf(e > 0.f ? e : expm1f(e));
                *reinterpret_cast<ushort4*>(out + (size_t)n * 64 + ct * 16 + g * 4) = o;
            }
        }
    } else {
        float* out = (float*)outv;
#pragma unroll
        for (int rt = 0; rt < 4; ++rt) {
            int n = nodebase + rt * 16 + l15;
            float v[CT * 4];
            float m = -3.4e38f;
#pragma unroll
            for (int ct = 0; ct < CT; ++ct)
#pragma unroll
                for (int r = 0; r < 4; ++r) {
                    int ch = ct * 16 + g * 4 + r;
                    float t = acc[rt][ct][r] + bv[ct][r];
                    v[ct * 4 + r] = t;
                    if (ch < COUT) m = fmaxf(m, t);
                }
            m = fmaxf(m, __shfl_xor(m, 16));
            m = fmaxf(m, __shfl_xor(m, 32));
            float s = 0.0f;
#pragma unroll
            for (int ct = 0; ct < CT; ++ct)
#pragma unroll
                for (int r = 0; r < 4; ++r) {
                    int ch = ct * 16 + g * 4 + r;
                    if (ch < COUT) s += expf(v[ct * 4 + r] - m);
                }
            s += __shfl_xor(s, 16);
            s += __shfl_xor(s, 32);
            float lse = m + logf(s);
            if (n >= N_NODES) continue;
#pragma unroll
            for (int ct = 0; ct < CT; ++ct) {
                int base = ct * 16 + g * 4;
                if (base + 4 <= COUT) {
                    float4 o;
                    o.x = v[ct * 4 + 0] - lse;
                    o.y = v[ct * 4 + 1] - lse;
                    o.z = v[ct * 4 + 2] - lse;
                    o.w = v[ct * 4 + 3] - lse;
                    *reinterpret_cast<float4*>(out + (size_t)n * COUT + base) = o;
                }
            }
        }
    }
}

extern "C" void kernel_launch(void* const* d_in, const int* in_sizes, int n_in,
                              void* d_out, int out_size, void* d_ws, size_t ws_size,
                              hipStream_t stream) {
    const float* x     = (const float*)d_in[0];
    const int*   ei    = (const int*)d_in[1];
    const float* ea    = (const float*)d_in[2];
    const float* W1    = (const float*)d_in[3];
    const float* root1 = (const float*)d_in[4];
    const float* b1    = (const float*)d_in[5];
    const float* W2    = (const float*)d_in[6];
    const float* root2 = (const float*)d_in[7];
    const float* b2    = (const float*)d_in[8];
    float* out = (float*)d_out;

    // workspace layout
    char* p = (char*)d_ws;
    int*   bucket_cur = (int*)p;            p += 512 * 4;
    int2*  binned  = (int2*)p;              p += (size_t)NBUK * BSTRIDE * 8;
    int2*  rec     = (int2*)p;              p += (size_t)N_EDGES * 8;
    int*   rowptr  = (int*)p;               p += (size_t)N_NODES * 4;
    int*   cnt     = (int*)p;               p += (size_t)N_NODES * 4;
    unsigned short* s01b = (unsigned short*)p;  p += (size_t)N_NODES * 128 * 2;
    unsigned short* xb   = (unsigned short*)p;  p += (size_t)N_NODES * 64 * 2;
    unsigned short* hprb = (unsigned short*)p;  p += (size_t)N_NODES * 64 * 2;
    unsigned short* Wt1  = (unsigned short*)p;  p += (size_t)64 * 192 * 2;
    unsigned short* Wt2  = (unsigned short*)p;  p += (size_t)48 * 192 * 2;

    // ---- prep ----
    x2bf16_kernel<<<(N_NODES * 16) / 256, 256, 0, stream>>>(x, xb);
    wt_kernel<<<48, 256, 0, stream>>>(W1, root1, Wt1, 64, 64 * 192);
    wt_kernel<<<36, 256, 0, stream>>>(W2, root2, Wt2, 40, 48 * 192);
    hipMemsetAsync(bucket_cur, 0, 512 * 4, stream);

    // ---- CSR build via 2-phase counting sort (contiguous writes only) ----
    bin_edges<<<NCHA, 256, 0, stream>>>(ei, ea, bucket_cur, binned);
    bucket_sort<<<NBUK, 512, 0, stream>>>(bucket_cur, binned, rec, rowptr, cnt);

    // ---- layer 1 ----
    pull_agg<<<(N_NODES * 64) / 256, 256, 0, stream>>>(rowptr, cnt, rec, xb, s01b);
    gemm_mfma<64, 4, 1><<<NB_SCAN, 256, 0, stream>>>(s01b, xb, Wt1, b1, hprb);

    // ---- layer 2 ----
    pull_agg<<<(N_NODES * 64) / 256, 256, 0, stream>>>(rowptr, cnt, rec, hprb, s01b);
    gemm_mfma<40, 3, 2><<<NB_SCAN, 256, 0, stream>>>(s01b, hprb, Wt2, b2, out);
}

// Round 9
// 200.172 us; speedup vs baseline: 2.4936x; 1.0140x over previous
//
#include <hip/hip_runtime.h>
#include <math.h>

#define N_NODES 100000
#define N_EDGES 1600000
#define NB_SCAN 391   // ceil(N_NODES/256)
#define CHUNK 4096
#define NCHA 391      // ceil(N_EDGES/CHUNK)
#define NBUK 256      // coarse dst buckets
#define DPB 391       // dsts per bucket (256*391 = 100096 >= 100000)
#define BSTRIDE 7168  // per-bucket capacity (mean 6250, sigma ~79)

typedef __attribute__((ext_vector_type(8))) short bf16x8;
typedef __attribute__((ext_vector_type(4))) float f32x4;

__device__ __forceinline__ unsigned short f2bf(float f) {
    union { float f; unsigned u; } v; v.f = f;
    unsigned r = v.u + 0x7FFF + ((v.u >> 16) & 1);  // round-nearest-even
    return (unsigned short)(r >> 16);
}
__device__ __forceinline__ float bf2f(unsigned short b) {
    union { unsigned u; float f; } v; v.u = ((unsigned)b) << 16;
    return v.f;
}

// ---------------------------------------------------------------------------
// f32 -> bf16 row copy of x (for the gather path).
// ---------------------------------------------------------------------------
__global__ void x2bf16_kernel(const float* __restrict__ x,
                              unsigned short* __restrict__ xb) {
    int i = blockIdx.x * 256 + threadIdx.x;
    if (i >= N_NODES * 16) return;
    float4 v = reinterpret_cast<const float4*>(x)[i];
    ushort4 o;
    o.x = f2bf(v.x); o.y = f2bf(v.y); o.z = f2bf(v.z); o.w = f2bf(v.w);
    reinterpret_cast<ushort4*>(xb)[i] = o;
}

// ---------------------------------------------------------------------------
// Weight transpose+cast: Wt[c][k] = {W[0],W[1],root}[k][c], bf16; pad rows 0.
// ---------------------------------------------------------------------------
__global__ void wt_kernel(const float* __restrict__ W, const float* __restrict__ root,
                          unsigned short* __restrict__ Wt, int COUT, int total) {
    int i = blockIdx.x * 256 + threadIdx.x;
    if (i >= total) return;
    int c = i / 192;
    int k = i - c * 192;
    float v = 0.0f;
    if (c < COUT)
        v = (k < 128) ? W[(k >> 6) * 64 * COUT + (k & 63) * COUT + c]
                      : root[(k - 128) * COUT + c];
    Wt[i] = f2bf(v);
}

// ---------------------------------------------------------------------------
// Phase A: bin edges into 256 coarse dst-buckets with LDS compaction, so all
// global writes are contiguous runs. Record: {src, u16<<16 | dst_local(10b)}.
// ---------------------------------------------------------------------------
__global__ __launch_bounds__(256) void bin_edges(const int* __restrict__ ei,
                                                 const float* __restrict__ ea,
                                                 int* __restrict__ bucket_cur,
                                                 int2* __restrict__ binned) {
    __shared__ int hist[NBUK];
    __shared__ int lbase[NBUK];
    __shared__ int lcur[NBUK];
    __shared__ int gbase[NBUK];
    __shared__ int2 stage[CHUNK];
    __shared__ unsigned char sbkt[CHUNK];
    int tid = threadIdx.x;
    int e0 = blockIdx.x * CHUNK;
    int nval = min(CHUNK, N_EDGES - e0);

    if (tid < NBUK) hist[tid] = 0;
    __syncthreads();
    for (int j = tid; j < nval; j += 256)
        atomicAdd(&hist[ei[N_EDGES + e0 + j] / DPB], 1);
    __syncthreads();
    if (tid < NBUK) lbase[tid] = hist[tid];
    __syncthreads();
    for (int off = 1; off < NBUK; off <<= 1) {
        int v = (tid < NBUK && tid >= off) ? lbase[tid - off] : 0;
        __syncthreads();
        if (tid < NBUK) lbase[tid] += v;
        __syncthreads();
    }
    if (tid < NBUK) {
        int ex = lbase[tid] - hist[tid];  // exclusive
        lbase[tid] = ex;
        lcur[tid]  = ex;
        gbase[tid] = atomicAdd(&bucket_cur[tid], hist[tid]);
    }
    __syncthreads();
    for (int j = tid; j < nval; j += 256) {
        int e = e0 + j;
        int d = ei[N_EDGES + e];
        int b = d / DPB;
        int dl = d - b * DPB;
        float u = ea[e];
        int uq = min((int)(u * 65536.0f + 0.5f), 65535);
        int pos = atomicAdd(&lcur[b], 1);
        stage[pos] = make_int2(ei[e], (uq << 16) | dl);
        sbkt[pos] = (unsigned char)b;
    }
    __syncthreads();
    for (int j = tid; j < nval; j += 256) {
        int b = sbkt[j];
        int gp = gbase[b] + (j - lbase[b]);
        if (gp < BSTRIDE)
            binned[(size_t)b * BSTRIDE + gp] = stage[j];
    }
}

// ---------------------------------------------------------------------------
// Phase B: per-bucket counting sort in LDS. Emits rowptr/cnt (global CSR) and
// dst-sorted rec = {src, u(f32)} with fully coalesced writes.
// ---------------------------------------------------------------------------
__global__ __launch_bounds__(512) void bucket_sort(const int* __restrict__ bucket_cur,
                                                   const int2* __restrict__ binned,
                                                   int2* __restrict__ rec,
                                                   int* __restrict__ rowptr,
                                                   int* __restrict__ cnt_g) {
    __shared__ int cntA[512];
    __shared__ int cntB[512];
    __shared__ int2 stage[BSTRIDE];
    int tid = threadIdx.x;
    int b = blockIdx.x;

    // scan bucket sizes for this bucket's global base
    cntA[tid] = (tid < NBUK) ? bucket_cur[tid] : 0;
    __syncthreads();
    cntB[tid] = cntA[tid];
    __syncthreads();
    for (int off = 1; off < 512; off <<= 1) {
        int v = (tid >= off) ? cntB[tid - off] : 0;
        __syncthreads();
        cntB[tid] += v;
        __syncthreads();
    }
    int base = (b == 0) ? 0 : cntB[b - 1];
    int m = min(cntA[b], BSTRIDE);
    __syncthreads();

    // per-dst histogram over this bucket's 391 dsts
    cntA[tid] = 0;
    __syncthreads();
    const int2* bin = binned + (size_t)b * BSTRIDE;
    for (int j = tid; j < m; j += 512)
        atomicAdd(&cntA[bin[j].y & 1023], 1);
    __syncthreads();
    cntB[tid] = cntA[tid];
    __syncthreads();
    for (int off = 1; off < 512; off <<= 1) {
        int v = (tid >= off) ? cntB[tid - off] : 0;
        __syncthreads();
        cntB[tid] += v;
        __syncthreads();
    }
    // exclusive offsets; emit CSR; init cursors
    {
        int ex = cntB[tid] - cntA[tid];
        int d = b * DPB + tid;
        if (tid < DPB && d < N_NODES) {
            rowptr[d] = base + ex;
            cnt_g[d]  = cntA[tid];
        }
        __syncthreads();
        cntB[tid] = ex;
    }
    __syncthreads();
    // place sorted into LDS
    for (int j = tid; j < m; j += 512) {
        int2 r = bin[j];
        int dl = r.y & 1023;
        float u = ((unsigned)r.y >> 16) * (1.0f / 65536.0f);
        int pos = atomicAdd(&cntB[dl], 1);
        if (pos < BSTRIDE) stage[pos] = make_int2(r.x, __float_as_int(u));
    }
    __syncthreads();
    // coalesced stream-out
    for (int j = tid; j < m; j += 512)
        rec[base + j] = stage[j];
}

// ---------------------------------------------------------------------------
// Pull aggregation v3: one wave per node; 8 lanes per edge (bf16x8 = 16B),
// 8 edges per batch, SOFTWARE-PIPELINED (next batch's rec + feature gather
// issued before current batch's math), algebra s=Σv / a1=Σu·v so the inner
// loop is 8 ADD + 8 FMA (a0 = s - a1 recovered post-reduce). Output bf16.
// ---------------------------------------------------------------------------
__global__ __launch_bounds__(256) void pull_agg(
        const int* __restrict__ rowptr, const int* __restrict__ cnt,
        const int2* __restrict__ rec, const unsigned short* __restrict__ featb,
        unsigned short* __restrict__ s01b) {
    int wid  = (blockIdx.x * 256 + threadIdx.x) >> 6;
    int lane = threadIdx.x & 63;
    if (wid >= N_NODES) return;
    int fg = lane & 7;    // 16B chunk (8 bf16) within the 128B row
    int eg = lane >> 3;   // edge subgroup 0..7
    int start = rowptr[wid];
    int deg   = cnt[wid];
    int end   = start + deg;
    const bf16x8* f8 = reinterpret_cast<const bf16x8*>(featb);
    float s[8], a1[8];
#pragma unroll
    for (int k = 0; k < 8; ++k) { s[k] = 0.0f; a1[k] = 0.0f; }

    int i = start + eg;
    if (i < end) {
        int2   r0 = rec[i];
        bf16x8 v0 = f8[((size_t)(unsigned)r0.x << 3) + fg];
        while (true) {
            int inext = i + 8;
            bool more = inext < end;
            int2   r1;
            bf16x8 v1;
            if (more) {                       // issue next batch's loads
                r1 = rec[inext];              // streaming (L2-hot)
                v1 = f8[((size_t)(unsigned)r1.x << 3) + fg];  // random gather
            }
            float u = __int_as_float(r0.y);   // math on current batch
#pragma unroll
            for (int k = 0; k < 8; ++k) {
                float v = bf2f((unsigned short)v0[k]);
                s[k] += v;
                a1[k] = fmaf(u, v, a1[k]);
            }
            if (!more) break;
            r0 = r1; v0 = v1; i = inext;
        }
    }
    // reduce across the 8 edge subgroups (xor 8, 16, 32)
#pragma unroll
    for (int k = 0; k < 8; ++k) {
        s[k]  += __shfl_xor(s[k], 8);
        s[k]  += __shfl_xor(s[k], 16);
        s[k]  += __shfl_xor(s[k], 32);
        a1[k] += __shfl_xor(a1[k], 8);
        a1[k] += __shfl_xor(a1[k], 16);
        a1[k] += __shfl_xor(a1[k], 32);
    }
    float dinv = 1.0f / fmaxf((float)deg, 1.0f);
    if (eg == 0) {
        bf16x8 o;
#pragma unroll
        for (int k = 0; k < 8; ++k) o[k] = (short)f2bf((s[k] - a1[k]) * dinv);
        *reinterpret_cast<bf16x8*>(s01b + (size_t)wid * 128 + fg * 8) = o;
    } else if (eg == 1) {
        bf16x8 o;
#pragma unroll
        for (int k = 0; k < 8; ++k) o[k] = (short)f2bf(a1[k] * dinv);
        *reinterpret_cast<bf16x8*>(s01b + (size_t)wid * 128 + 64 + fg * 8) = o;
    }
}

// ---------------------------------------------------------------------------
// MFMA node transform (per block 256 nodes; wave owns 64). K=192 in 6 steps.
// D = Wt-frag x z-frag = C^T: lane holds node = base+(lane&15), channels
// ct*16 + (lane>>4)*4 + reg. ACT=1: ELU->bf16. ACT=2: log_softmax->f32.
// ---------------------------------------------------------------------------
template<int COUT, int CT, int ACT>
__global__ __launch_bounds__(256) void gemm_mfma(
        const unsigned short* __restrict__ s01b,
        const unsigned short* __restrict__ featb,
        const unsigned short* __restrict__ Wt,
        const float* __restrict__ bias, void* __restrict__ outv) {
    int lane = threadIdx.x & 63;
    int wave = threadIdx.x >> 6;
    int l15  = lane & 15;
    int g    = lane >> 4;
    int nodebase = blockIdx.x * 256 + wave * 64;

    f32x4 acc[4][CT];
#pragma unroll
    for (int rt = 0; rt < 4; ++rt)
#pragma unroll
        for (int ct = 0; ct < CT; ++ct) acc[rt][ct] = (f32x4){0.f, 0.f, 0.f, 0.f};

#pragma unroll
    for (int ks = 0; ks < 6; ++ks) {
        int kk = ks * 32 + g * 8;
        bf16x8 zfrag[4];
#pragma unroll
        for (int rt = 0; rt < 4; ++rt) {
            int n = nodebase + rt * 16 + l15;
            if (n >= N_NODES) n = N_NODES - 1;
            const unsigned short* p = (kk < 128)
                ? (s01b + (size_t)n * 128 + kk)
                : (featb + (size_t)n * 64 + (kk - 128));
            zfrag[rt] = *reinterpret_cast<const bf16x8*>(p);
        }
        bf16x8 wfrag[CT];
#pragma unroll
        for (int ct = 0; ct < CT; ++ct)
            wfrag[ct] = *reinterpret_cast<const bf16x8*>(Wt + (size_t)(ct * 16 + l15) * 192 + kk);
#pragma unroll
        for (int rt = 0; rt < 4; ++rt)
#pragma unroll
            for (int ct = 0; ct < CT; ++ct)
                acc[rt][ct] = __builtin_amdgcn_mfma_f32_16x16x32_bf16(
                    wfrag[ct], zfrag[rt], acc[rt][ct], 0, 0, 0);
    }

    f32x4 bv[CT];
#pragma unroll
    for (int ct = 0; ct < CT; ++ct) {
        int base = ct * 16 + g * 4;
        if (base + 4 <= COUT) {
            float4 b = *reinterpret_cast<const float4*>(bias + base);
            bv[ct] = (f32x4){b.x, b.y, b.z, b.w};
        } else {
            bv[ct] = (f32x4){0.f, 0.f, 0.f, 0.f};
        }
    }

    if (ACT == 1) {
        unsigned short* out = (unsigned short*)outv;
#pragma unroll
        for (int rt = 0; rt < 4; ++rt) {
            int n = nodebase + rt * 16 + l15;
            if (n >= N_NODES) continue;
#pragma unroll
            for (int ct = 0; ct < CT; ++ct) {
                f32x4 v = acc[rt][ct] + bv[ct];
                ushort4 o;
                float e;
                e = v[0]; o.x = f2bf(e > 0.f ? e : expm1f(e));
                e = v[1]; o.y = f2bf(e > 0.f ? e : expm1f(e));
                e = v[2]; o.z = f2bf(e > 0.f ? e : expm1f(e));
                e = v[3]; o.w = f2bf(e > 0.f ? e : expm1f(e));
                *reinterpret_cast<ushort4*>(out + (size_t)n * 64 + ct * 16 + g * 4) = o;
            }
        }
    } else {
        float* out = (float*)outv;
#pragma unroll
        for (int rt = 0; rt < 4; ++rt) {
            int n = nodebase + rt * 16 + l15;
            float v[CT * 4];
            float m = -3.4e38f;
#pragma unroll
            for (int ct = 0; ct < CT; ++ct)
#pragma unroll
                for (int r = 0; r < 4; ++r) {
                    int ch = ct * 16 + g * 4 + r;
                    float t = acc[rt][ct][r] + bv[ct][r];
                    v[ct * 4 + r] = t;
                    if (ch < COUT) m = fmaxf(m, t);
                }
            m = fmaxf(m, __shfl_xor(m, 16));
            m = fmaxf(m, __shfl_xor(m, 32));
            float s = 0.0f;
#pragma unroll
            for (int ct = 0; ct < CT; ++ct)
#pragma unroll
                for (int r = 0; r < 4; ++r) {
                    int ch = ct * 16 + g * 4 + r;
                    if (ch < COUT) s += expf(v[ct * 4 + r] - m);
                }
            s += __shfl_xor(s, 16);
            s += __shfl_xor(s, 32);
            float lse = m + logf(s);
            if (n >= N_NODES) continue;
#pragma unroll
            for (int ct = 0; ct < CT; ++ct) {
                int base = ct * 16 + g * 4;
                if (base + 4 <= COUT) {
                    float4 o;
                    o.x = v[ct * 4 + 0] - lse;
                    o.y = v[ct * 4 + 1] - lse;
                    o.z = v[ct * 4 + 2] - lse;
                    o.w = v[ct * 4 + 3] - lse;
                    *reinterpret_cast<float4*>(out + (size_t)n * COUT + base) = o;
                }
            }
        }
    }
}

extern "C" void kernel_launch(void* const* d_in, const int* in_sizes, int n_in,
                              void* d_out, int out_size, void* d_ws, size_t ws_size,
                              hipStream_t stream) {
    const float* x     = (const float*)d_in[0];
    const int*   ei    = (const int*)d_in[1];
    const float* ea    = (const float*)d_in[2];
    const float* W1    = (const float*)d_in[3];
    const float* root1 = (const float*)d_in[4];
    const float* b1    = (const float*)d_in[5];
    const float* W2    = (const float*)d_in[6];
    const float* root2 = (const float*)d_in[7];
    const float* b2    = (const float*)d_in[8];
    float* out = (float*)d_out;

    // workspace layout
    char* p = (char*)d_ws;
    int*   bucket_cur = (int*)p;            p += 512 * 4;
    int2*  binned  = (int2*)p;              p += (size_t)NBUK * BSTRIDE * 8;
    int2*  rec     = (int2*)p;              p += (size_t)N_EDGES * 8;
    int*   rowptr  = (int*)p;               p += (size_t)N_NODES * 4;
    int*   cnt     = (int*)p;               p += (size_t)N_NODES * 4;
    unsigned short* s01b = (unsigned short*)p;  p += (size_t)N_NODES * 128 * 2;
    unsigned short* xb   = (unsigned short*)p;  p += (size_t)N_NODES * 64 * 2;
    unsigned short* hprb = (unsigned short*)p;  p += (size_t)N_NODES * 64 * 2;
    unsigned short* Wt1  = (unsigned short*)p;  p += (size_t)64 * 192 * 2;
    unsigned short* Wt2  = (unsigned short*)p;  p += (size_t)48 * 192 * 2;

    // ---- prep ----
    x2bf16_kernel<<<(N_NODES * 16) / 256, 256, 0, stream>>>(x, xb);
    wt_kernel<<<48, 256, 0, stream>>>(W1, root1, Wt1, 64, 64 * 192);
    wt_kernel<<<36, 256, 0, stream>>>(W2, root2, Wt2, 40, 48 * 192);
    hipMemsetAsync(bucket_cur, 0, 512 * 4, stream);

    // ---- CSR build via 2-phase counting sort (contiguous writes only) ----
    bin_edges<<<NCHA, 256, 0, stream>>>(ei, ea, bucket_cur, binned);
    bucket_sort<<<NBUK, 512, 0, stream>>>(bucket_cur, binned, rec, rowptr, cnt);

    // ---- layer 1 ----
    pull_agg<<<(N_NODES * 64) / 256, 256, 0, stream>>>(rowptr, cnt, rec, xb, s01b);
    gemm_mfma<64, 4, 1><<<NB_SCAN, 256, 0, stream>>>(s01b, xb, Wt1, b1, hprb);

    // ---- layer 2 ----
    pull_agg<<<(N_NODES * 64) / 256, 256, 0, stream>>>(rowptr, cnt, rec, hprb, s01b);
    gemm_mfma<40, 3, 2><<<NB_SCAN, 256, 0, stream>>>(s01b, hprb, Wt2, b2, out);
}

// Round 10
// 181.741 us; speedup vs baseline: 2.7465x; 1.1014x over previous
//
#include <hip/hip_runtime.h>
#include <math.h>

#define N_NODES 100000
#define N_EDGES 1600000
#define NB_SCAN 391   // ceil(N_NODES/256)
#define CHUNK 4096
#define NCHA 391      // ceil(N_EDGES/CHUNK)
#define NBUK 256      // coarse dst buckets
#define DPB 391       // dsts per bucket (256*391 = 100096 >= 100000)
#define BSTRIDE 7168  // per-bucket capacity (mean 6250, sigma ~79)

typedef __attribute__((ext_vector_type(8))) short bf16x8;
typedef __attribute__((ext_vector_type(4))) float f32x4;

__device__ __forceinline__ unsigned short f2bf(float f) {
    union { float f; unsigned u; } v; v.f = f;
    unsigned r = v.u + 0x7FFF + ((v.u >> 16) & 1);  // round-nearest-even
    return (unsigned short)(r >> 16);
}
__device__ __forceinline__ float bf2f(unsigned short b) {
    union { unsigned u; float f; } v; v.u = ((unsigned)b) << 16;
    return v.f;
}

// ---------------------------------------------------------------------------
// f32 -> bf16 row copy of x (for the gather path).
// ---------------------------------------------------------------------------
__global__ void x2bf16_kernel(const float* __restrict__ x,
                              unsigned short* __restrict__ xb) {
    int i = blockIdx.x * 256 + threadIdx.x;
    if (i >= N_NODES * 16) return;
    float4 v = reinterpret_cast<const float4*>(x)[i];
    ushort4 o;
    o.x = f2bf(v.x); o.y = f2bf(v.y); o.z = f2bf(v.z); o.w = f2bf(v.w);
    reinterpret_cast<ushort4*>(xb)[i] = o;
}

// ---------------------------------------------------------------------------
// Weight transpose+cast: Wt[c][k] = {W[0],W[1],root}[k][c], bf16; pad rows 0.
// ---------------------------------------------------------------------------
__global__ void wt_kernel(const float* __restrict__ W, const float* __restrict__ root,
                          unsigned short* __restrict__ Wt, int COUT, int total) {
    int i = blockIdx.x * 256 + threadIdx.x;
    if (i >= total) return;
    int c = i / 192;
    int k = i - c * 192;
    float v = 0.0f;
    if (c < COUT)
        v = (k < 128) ? W[(k >> 6) * 64 * COUT + (k & 63) * COUT + c]
                      : root[(k - 128) * COUT + c];
    Wt[i] = f2bf(v);
}

// ---------------------------------------------------------------------------
// Phase A: bin edges into 256 coarse dst-buckets with LDS compaction, so all
// global writes are contiguous runs. Record: {src, u16<<16 | dst_local(10b)}.
// ---------------------------------------------------------------------------
__global__ __launch_bounds__(256) void bin_edges(const int* __restrict__ ei,
                                                 const float* __restrict__ ea,
                                                 int* __restrict__ bucket_cur,
                                                 int2* __restrict__ binned) {
    __shared__ int hist[NBUK];
    __shared__ int lbase[NBUK];
    __shared__ int lcur[NBUK];
    __shared__ int gbase[NBUK];
    __shared__ int2 stage[CHUNK];
    __shared__ unsigned char sbkt[CHUNK];
    int tid = threadIdx.x;
    int e0 = blockIdx.x * CHUNK;
    int nval = min(CHUNK, N_EDGES - e0);

    if (tid < NBUK) hist[tid] = 0;
    __syncthreads();
    for (int j = tid; j < nval; j += 256)
        atomicAdd(&hist[ei[N_EDGES + e0 + j] / DPB], 1);
    __syncthreads();
    if (tid < NBUK) lbase[tid] = hist[tid];
    __syncthreads();
    for (int off = 1; off < NBUK; off <<= 1) {
        int v = (tid < NBUK && tid >= off) ? lbase[tid - off] : 0;
        __syncthreads();
        if (tid < NBUK) lbase[tid] += v;
        __syncthreads();
    }
    if (tid < NBUK) {
        int ex = lbase[tid] - hist[tid];  // exclusive
        lbase[tid] = ex;
        lcur[tid]  = ex;
        gbase[tid] = atomicAdd(&bucket_cur[tid], hist[tid]);
    }
    __syncthreads();
    for (int j = tid; j < nval; j += 256) {
        int e = e0 + j;
        int d = ei[N_EDGES + e];
        int b = d / DPB;
        int dl = d - b * DPB;
        float u = ea[e];
        int uq = min((int)(u * 65536.0f + 0.5f), 65535);
        int pos = atomicAdd(&lcur[b], 1);
        stage[pos] = make_int2(ei[e], (uq << 16) | dl);
        sbkt[pos] = (unsigned char)b;
    }
    __syncthreads();
    for (int j = tid; j < nval; j += 256) {
        int b = sbkt[j];
        int gp = gbase[b] + (j - lbase[b]);
        if (gp < BSTRIDE)
            binned[(size_t)b * BSTRIDE + gp] = stage[j];
    }
}

// ---------------------------------------------------------------------------
// Phase B: per-bucket counting sort in LDS. Emits rowptr/cnt (global CSR) and
// dst-sorted rec = {src, u(f32)} with fully coalesced writes.
// ---------------------------------------------------------------------------
__global__ __launch_bounds__(512) void bucket_sort(const int* __restrict__ bucket_cur,
                                                   const int2* __restrict__ binned,
                                                   int2* __restrict__ rec,
                                                   int* __restrict__ rowptr,
                                                   int* __restrict__ cnt_g) {
    __shared__ int cntA[512];
    __shared__ int cntB[512];
    __shared__ int2 stage[BSTRIDE];
    int tid = threadIdx.x;
    int b = blockIdx.x;

    // scan bucket sizes for this bucket's global base
    cntA[tid] = (tid < NBUK) ? bucket_cur[tid] : 0;
    __syncthreads();
    cntB[tid] = cntA[tid];
    __syncthreads();
    for (int off = 1; off < 512; off <<= 1) {
        int v = (tid >= off) ? cntB[tid - off] : 0;
        __syncthreads();
        cntB[tid] += v;
        __syncthreads();
    }
    int base = (b == 0) ? 0 : cntB[b - 1];
    int m = min(cntA[b], BSTRIDE);
    __syncthreads();

    // per-dst histogram over this bucket's 391 dsts
    cntA[tid] = 0;
    __syncthreads();
    const int2* bin = binned + (size_t)b * BSTRIDE;
    for (int j = tid; j < m; j += 512)
        atomicAdd(&cntA[bin[j].y & 1023], 1);
    __syncthreads();
    cntB[tid] = cntA[tid];
    __syncthreads();
    for (int off = 1; off < 512; off <<= 1) {
        int v = (tid >= off) ? cntB[tid - off] : 0;
        __syncthreads();
        cntB[tid] += v;
        __syncthreads();
    }
    // exclusive offsets; emit CSR; init cursors
    {
        int ex = cntB[tid] - cntA[tid];
        int d = b * DPB + tid;
        if (tid < DPB && d < N_NODES) {
            rowptr[d] = base + ex;
            cnt_g[d]  = cntA[tid];
        }
        __syncthreads();
        cntB[tid] = ex;
    }
    __syncthreads();
    // place sorted into LDS
    for (int j = tid; j < m; j += 512) {
        int2 r = bin[j];
        int dl = r.y & 1023;
        float u = ((unsigned)r.y >> 16) * (1.0f / 65536.0f);
        int pos = atomicAdd(&cntB[dl], 1);
        if (pos < BSTRIDE) stage[pos] = make_int2(r.x, __float_as_int(u));
    }
    __syncthreads();
    // coalesced stream-out
    for (int j = tid; j < m; j += 512)
        rec[base + j] = stage[j];
}

// ---------------------------------------------------------------------------
// Pull aggregation v4: wave = 8 nodes; each 8-lane group owns ONE node and
// iterates its edge list serially with a 2-deep software pipeline (next rec +
// next 16B feature chunk issued before current math). Lane fg accumulates
// feats [8fg, 8fg+8) of its node across all edges -> ZERO cross-lane
// shuffles; direct bf16x8 stores. Algebra: s=Σv, a1=Σu·v, a0 = s - a1.
// ---------------------------------------------------------------------------
__global__ __launch_bounds__(256) void pull_agg(
        const int* __restrict__ rowptr, const int* __restrict__ cnt,
        const int2* __restrict__ rec, const unsigned short* __restrict__ featb,
        unsigned short* __restrict__ s01b) {
    int wave_id = (blockIdx.x * 256 + threadIdx.x) >> 6;
    int lane = threadIdx.x & 63;
    int fg = lane & 7;    // 16B chunk (8 bf16) within the 128B row
    int eg = lane >> 3;   // node subgroup 0..7
    int n = wave_id * 8 + eg;
    bool valid = n < N_NODES;
    int start = 0, deg = 0;
    if (valid) { start = rowptr[n]; deg = cnt[n]; }
    int end = start + deg;
    const bf16x8* f8 = reinterpret_cast<const bf16x8*>(featb);
    float s[8], a1[8];
#pragma unroll
    for (int k = 0; k < 8; ++k) { s[k] = 0.0f; a1[k] = 0.0f; }

    int i = start;
    if (i < end) {
        int2   r0 = rec[i];
        bf16x8 v0 = f8[((size_t)(unsigned)r0.x << 3) + fg];
        while (true) {
            int inext = i + 1;
            bool more = inext < end;
            int2   r1;
            bf16x8 v1;
            if (more) {                       // issue next edge's loads
                r1 = rec[inext];
                v1 = f8[((size_t)(unsigned)r1.x << 3) + fg];
            }
            float u = __int_as_float(r0.y);   // math on current edge
#pragma unroll
            for (int k = 0; k < 8; ++k) {
                float v = bf2f((unsigned short)v0[k]);
                s[k] += v;
                a1[k] = fmaf(u, v, a1[k]);
            }
            if (!more) break;
            r0 = r1; v0 = v1; i = inext;
        }
    }
    if (valid) {
        float dinv = 1.0f / fmaxf((float)deg, 1.0f);
        bf16x8 o0, o1;
#pragma unroll
        for (int k = 0; k < 8; ++k) {
            o0[k] = (short)f2bf((s[k] - a1[k]) * dinv);
            o1[k] = (short)f2bf(a1[k] * dinv);
        }
        *reinterpret_cast<bf16x8*>(s01b + (size_t)n * 128 + fg * 8) = o0;
        *reinterpret_cast<bf16x8*>(s01b + (size_t)n * 128 + 64 + fg * 8) = o1;
    }
}

// ---------------------------------------------------------------------------
// MFMA node transform (per block 256 nodes; wave owns 64). K=192 in 6 steps.
// D = Wt-frag x z-frag = C^T: lane holds node = base+(lane&15), channels
// ct*16 + (lane>>4)*4 + reg. ACT=1: ELU->bf16. ACT=2: log_softmax->f32.
// ---------------------------------------------------------------------------
template<int COUT, int CT, int ACT>
__global__ __launch_bounds__(256) void gemm_mfma(
        const unsigned short* __restrict__ s01b,
        const unsigned short* __restrict__ featb,
        const unsigned short* __restrict__ Wt,
        const float* __restrict__ bias, void* __restrict__ outv) {
    int lane = threadIdx.x & 63;
    int wave = threadIdx.x >> 6;
    int l15  = lane & 15;
    int g    = lane >> 4;
    int nodebase = blockIdx.x * 256 + wave * 64;

    f32x4 acc[4][CT];
#pragma unroll
    for (int rt = 0; rt < 4; ++rt)
#pragma unroll
        for (int ct = 0; ct < CT; ++ct) acc[rt][ct] = (f32x4){0.f, 0.f, 0.f, 0.f};

#pragma unroll
    for (int ks = 0; ks < 6; ++ks) {
        int kk = ks * 32 + g * 8;
        bf16x8 zfrag[4];
#pragma unroll
        for (int rt = 0; rt < 4; ++rt) {
            int n = nodebase + rt * 16 + l15;
            if (n >= N_NODES) n = N_NODES - 1;
            const unsigned short* p = (kk < 128)
                ? (s01b + (size_t)n * 128 + kk)
                : (featb + (size_t)n * 64 + (kk - 128));
            zfrag[rt] = *reinterpret_cast<const bf16x8*>(p);
        }
        bf16x8 wfrag[CT];
#pragma unroll
        for (int ct = 0; ct < CT; ++ct)
            wfrag[ct] = *reinterpret_cast<const bf16x8*>(Wt + (size_t)(ct * 16 + l15) * 192 + kk);
#pragma unroll
        for (int rt = 0; rt < 4; ++rt)
#pragma unroll
            for (int ct = 0; ct < CT; ++ct)
                acc[rt][ct] = __builtin_amdgcn_mfma_f32_16x16x32_bf16(
                    wfrag[ct], zfrag[rt], acc[rt][ct], 0, 0, 0);
    }

    f32x4 bv[CT];
#pragma unroll
    for (int ct = 0; ct < CT; ++ct) {
        int base = ct * 16 + g * 4;
        if (base + 4 <= COUT) {
            float4 b = *reinterpret_cast<const float4*>(bias + base);
            bv[ct] = (f32x4){b.x, b.y, b.z, b.w};
        } else {
            bv[ct] = (f32x4){0.f, 0.f, 0.f, 0.f};
        }
    }

    if (ACT == 1) {
        unsigned short* out = (unsigned short*)outv;
#pragma unroll
        for (int rt = 0; rt < 4; ++rt) {
            int n = nodebase + rt * 16 + l15;
            if (n >= N_NODES) continue;
#pragma unroll
            for (int ct = 0; ct < CT; ++ct) {
                f32x4 v = acc[rt][ct] + bv[ct];
                ushort4 o;
                float e;
                e = v[0]; o.x = f2bf(e > 0.f ? e : expm1f(e));
                e = v[1]; o.y = f2bf(e > 0.f ? e : expm1f(e));
                e = v[2]; o.z = f2bf(e > 0.f ? e : expm1f(e));
                e = v[3]; o.w = f2bf(e > 0.f ? e : expm1f(e));
                *reinterpret_cast<ushort4*>(out + (size_t)n * 64 + ct * 16 + g * 4) = o;
            }
        }
    } else {
        float* out = (float*)outv;
#pragma unroll
        for (int rt = 0; rt < 4; ++rt) {
            int n = nodebase + rt * 16 + l15;
            float v[CT * 4];
            float m = -3.4e38f;
#pragma unroll
            for (int ct = 0; ct < CT; ++ct)
#pragma unroll
                for (int r = 0; r < 4; ++r) {
                    int ch = ct * 16 + g * 4 + r;
                    float t = acc[rt][ct][r] + bv[ct][r];
                    v[ct * 4 + r] = t;
                    if (ch < COUT) m = fmaxf(m, t);
                }
            m = fmaxf(m, __shfl_xor(m, 16));
            m = fmaxf(m, __shfl_xor(m, 32));
            float s = 0.0f;
#pragma unroll
            for (int ct = 0; ct < CT; ++ct)
#pragma unroll
                for (int r = 0; r < 4; ++r) {
                    int ch = ct * 16 + g * 4 + r;
                    if (ch < COUT) s += expf(v[ct * 4 + r] - m);
                }
            s += __shfl_xor(s, 16);
            s += __shfl_xor(s, 32);
            float lse = m + logf(s);
            if (n >= N_NODES) continue;
#pragma unroll
            for (int ct = 0; ct < CT; ++ct) {
                int base = ct * 16 + g * 4;
                if (base + 4 <= COUT) {
                    float4 o;
                    o.x = v[ct * 4 + 0] - lse;
                    o.y = v[ct * 4 + 1] - lse;
                    o.z = v[ct * 4 + 2] - lse;
                    o.w = v[ct * 4 + 3] - lse;
                    *reinterpret_cast<float4*>(out + (size_t)n * COUT + base) = o;
                }
            }
        }
    }
}

extern "C" void kernel_launch(void* const* d_in, const int* in_sizes, int n_in,
                              void* d_out, int out_size, void* d_ws, size_t ws_size,
                              hipStream_t stream) {
    const float* x     = (const float*)d_in[0];
    const int*   ei    = (const int*)d_in[1];
    const float* ea    = (const float*)d_in[2];
    const float* W1    = (const float*)d_in[3];
    const float* root1 = (const float*)d_in[4];
    const float* b1    = (const float*)d_in[5];
    const float* W2    = (const float*)d_in[6];
    const float* root2 = (const float*)d_in[7];
    const float* b2    = (const float*)d_in[8];
    float* out = (float*)d_out;

    // workspace layout
    char* p = (char*)d_ws;
    int*   bucket_cur = (int*)p;            p += 512 * 4;
    int2*  binned  = (int2*)p;              p += (size_t)NBUK * BSTRIDE * 8;
    int2*  rec     = (int2*)p;              p += (size_t)N_EDGES * 8;
    int*   rowptr  = (int*)p;               p += (size_t)N_NODES * 4;
    int*   cnt     = (int*)p;               p += (size_t)N_NODES * 4;
    unsigned short* s01b = (unsigned short*)p;  p += (size_t)N_NODES * 128 * 2;
    unsigned short* xb   = (unsigned short*)p;  p += (size_t)N_NODES * 64 * 2;
    unsigned short* hprb = (unsigned short*)p;  p += (size_t)N_NODES * 64 * 2;
    unsigned short* Wt1  = (unsigned short*)p;  p += (size_t)64 * 192 * 2;
    unsigned short* Wt2  = (unsigned short*)p;  p += (size_t)48 * 192 * 2;

    // ---- prep ----
    x2bf16_kernel<<<(N_NODES * 16) / 256, 256, 0, stream>>>(x, xb);
    wt_kernel<<<48, 256, 0, stream>>>(W1, root1, Wt1, 64, 64 * 192);
    wt_kernel<<<36, 256, 0, stream>>>(W2, root2, Wt2, 40, 48 * 192);
    hipMemsetAsync(bucket_cur, 0, 512 * 4, stream);

    // ---- CSR build via 2-phase counting sort (contiguous writes only) ----
    bin_edges<<<NCHA, 256, 0, stream>>>(ei, ea, bucket_cur, binned);
    bucket_sort<<<NBUK, 512, 0, stream>>>(bucket_cur, binned, rec, rowptr, cnt);

    // ---- layer 1 ----  (wave = 8 nodes -> 3125 blocks)
    pull_agg<<<(N_NODES + 31) / 32, 256, 0, stream>>>(rowptr, cnt, rec, xb, s01b);
    gemm_mfma<64, 4, 1><<<NB_SCAN, 256, 0, stream>>>(s01b, xb, Wt1, b1, hprb);

    // ---- layer 2 ----
    pull_agg<<<(N_NODES + 31) / 32, 256, 0, stream>>>(rowptr, cnt, rec, hprb, s01b);
    gemm_mfma<40, 3, 2><<<NB_SCAN, 256, 0, stream>>>(s01b, hprb, Wt2, b2, out);
}

// Round 11
// 163.380 us; speedup vs baseline: 3.0551x; 1.1124x over previous
//
#include <hip/hip_runtime.h>
#include <math.h>

#define N_NODES 100000
#define N_EDGES 1600000
#define NB_SCAN 391   // ceil(N_NODES/256)
#define CHUNK 4096
#define NCHA 391      // ceil(N_EDGES/CHUNK)
#define NBUK 256      // coarse dst buckets
#define DPB 391       // dsts per bucket (256*391 = 100096 >= 100000)
#define BSTRIDE 7168  // per-bucket capacity (mean 6250, sigma ~79)
#define TILE_N 25000  // src tile (3.2 MB bf16, fits 4 MB XCD L2)

typedef __attribute__((ext_vector_type(8))) short bf16x8;
typedef __attribute__((ext_vector_type(4))) float f32x4;

__device__ __forceinline__ unsigned short f2bf(float f) {
    union { float f; unsigned u; } v; v.f = f;
    unsigned r = v.u + 0x7FFF + ((v.u >> 16) & 1);  // round-nearest-even
    return (unsigned short)(r >> 16);
}
__device__ __forceinline__ float bf2f(unsigned short b) {
    union { unsigned u; float f; } v; v.u = ((unsigned)b) << 16;
    return v.f;
}

// ---------------------------------------------------------------------------
// f32 -> bf16 row copy of x (for the gather path).
// ---------------------------------------------------------------------------
__global__ void x2bf16_kernel(const float* __restrict__ x,
                              unsigned short* __restrict__ xb) {
    int i = blockIdx.x * 256 + threadIdx.x;
    if (i >= N_NODES * 16) return;
    float4 v = reinterpret_cast<const float4*>(x)[i];
    ushort4 o;
    o.x = f2bf(v.x); o.y = f2bf(v.y); o.z = f2bf(v.z); o.w = f2bf(v.w);
    reinterpret_cast<ushort4*>(xb)[i] = o;
}

// ---------------------------------------------------------------------------
// Weight transpose+cast: Wt[c][k] = {W[0],W[1],root}[k][c], bf16; pad rows 0.
// ---------------------------------------------------------------------------
__global__ void wt_kernel(const float* __restrict__ W, const float* __restrict__ root,
                          unsigned short* __restrict__ Wt, int COUT, int total) {
    int i = blockIdx.x * 256 + threadIdx.x;
    if (i >= total) return;
    int c = i / 192;
    int k = i - c * 192;
    float v = 0.0f;
    if (c < COUT)
        v = (k < 128) ? W[(k >> 6) * 64 * COUT + (k & 63) * COUT + c]
                      : root[(k - 128) * COUT + c];
    Wt[i] = f2bf(v);
}

// ---------------------------------------------------------------------------
// Phase A: bin edges into 256 coarse dst-buckets with LDS compaction, so all
// global writes are contiguous runs. Record: {src, u16<<16 | dst_local(10b)}.
// ---------------------------------------------------------------------------
__global__ __launch_bounds__(256) void bin_edges(const int* __restrict__ ei,
                                                 const float* __restrict__ ea,
                                                 int* __restrict__ bucket_cur,
                                                 int2* __restrict__ binned) {
    __shared__ int hist[NBUK];
    __shared__ int lbase[NBUK];
    __shared__ int lcur[NBUK];
    __shared__ int gbase[NBUK];
    __shared__ int2 stage[CHUNK];
    __shared__ unsigned char sbkt[CHUNK];
    int tid = threadIdx.x;
    int e0 = blockIdx.x * CHUNK;
    int nval = min(CHUNK, N_EDGES - e0);

    if (tid < NBUK) hist[tid] = 0;
    __syncthreads();
    for (int j = tid; j < nval; j += 256)
        atomicAdd(&hist[ei[N_EDGES + e0 + j] / DPB], 1);
    __syncthreads();
    if (tid < NBUK) lbase[tid] = hist[tid];
    __syncthreads();
    for (int off = 1; off < NBUK; off <<= 1) {
        int v = (tid < NBUK && tid >= off) ? lbase[tid - off] : 0;
        __syncthreads();
        if (tid < NBUK) lbase[tid] += v;
        __syncthreads();
    }
    if (tid < NBUK) {
        int ex = lbase[tid] - hist[tid];  // exclusive
        lbase[tid] = ex;
        lcur[tid]  = ex;
        gbase[tid] = atomicAdd(&bucket_cur[tid], hist[tid]);
    }
    __syncthreads();
    for (int j = tid; j < nval; j += 256) {
        int e = e0 + j;
        int d = ei[N_EDGES + e];
        int b = d / DPB;
        int dl = d - b * DPB;
        float u = ea[e];
        int uq = min((int)(u * 65536.0f + 0.5f), 65535);
        int pos = atomicAdd(&lcur[b], 1);
        stage[pos] = make_int2(ei[e], (uq << 16) | dl);
        sbkt[pos] = (unsigned char)b;
    }
    __syncthreads();
    for (int j = tid; j < nval; j += 256) {
        int b = sbkt[j];
        int gp = gbase[b] + (j - lbase[b]);
        if (gp < BSTRIDE)
            binned[(size_t)b * BSTRIDE + gp] = stage[j];
    }
}

// ---------------------------------------------------------------------------
// Phase B: per-bucket counting sort over key = dst_local*4 + src_tile.
// Emits rowptr[d] (base of the node's records) and cnt[d] (total deg) — the
// per-node record list is ordered by src tile, so the pull loop's early
// iterations hit tile 0 (L2-resident) across all waves simultaneously.
// ---------------------------------------------------------------------------
__global__ __launch_bounds__(512) void bucket_sort(const int* __restrict__ bucket_cur,
                                                   const int2* __restrict__ binned,
                                                   int2* __restrict__ rec,
                                                   int* __restrict__ rowptr,
                                                   int* __restrict__ cnt_g) {
    __shared__ int keycnt[1600];
    __shared__ int tsum[512];
    __shared__ int2 stage[BSTRIDE];
    int tid = threadIdx.x;
    int b = blockIdx.x;

    // global base of this bucket = exclusive prefix of bucket sizes
    tsum[tid] = (tid < NBUK) ? bucket_cur[tid] : 0;
    __syncthreads();
    for (int off = 1; off < 512; off <<= 1) {
        int v = (tid >= off) ? tsum[tid - off] : 0;
        __syncthreads();
        tsum[tid] += v;
        __syncthreads();
    }
    int base = (b == 0) ? 0 : tsum[b - 1];
    int m = min(bucket_cur[b], BSTRIDE);
    __syncthreads();

    for (int k = tid; k < 1600; k += 512) keycnt[k] = 0;
    __syncthreads();
    const int2* bin = binned + (size_t)b * BSTRIDE;
    for (int j = tid; j < m; j += 512) {
        int2 r = bin[j];
        int key = ((r.y & 1023) << 2) | ((unsigned)r.x / TILE_N);
        atomicAdd(&keycnt[key], 1);
    }
    __syncthreads();
    int k0 = tid << 2;
    int c0 = 0, c1 = 0, c2 = 0, c3 = 0;
    if (tid < DPB) {
        c0 = keycnt[k0]; c1 = keycnt[k0 + 1];
        c2 = keycnt[k0 + 2]; c3 = keycnt[k0 + 3];
    }
    int s4 = c0 + c1 + c2 + c3;
    tsum[tid] = s4;
    __syncthreads();
    for (int off = 1; off < 512; off <<= 1) {
        int v = (tid >= off) ? tsum[tid - off] : 0;
        __syncthreads();
        tsum[tid] += v;
        __syncthreads();
    }
    if (tid < DPB) {
        int p = tsum[tid] - s4;  // exclusive over keys
        int d = b * DPB + tid;
        if (d < N_NODES) {
            rowptr[d] = base + p;
            cnt_g[d]  = s4;
        }
        keycnt[k0] = p;     p += c0;
        keycnt[k0 + 1] = p; p += c1;
        keycnt[k0 + 2] = p; p += c2;
        keycnt[k0 + 3] = p;
    }
    __syncthreads();
    for (int j = tid; j < m; j += 512) {
        int2 r = bin[j];
        int key = ((r.y & 1023) << 2) | ((unsigned)r.x / TILE_N);
        float u = ((unsigned)r.y >> 16) * (1.0f / 65536.0f);
        int pos = atomicAdd(&keycnt[key], 1);
        if (pos < BSTRIDE) stage[pos] = make_int2(r.x, __float_as_int(u));
    }
    __syncthreads();
    for (int j = tid; j < m; j += 512)
        rec[base + j] = stage[j];
}

// ---------------------------------------------------------------------------
// Pull aggregation v5: wave = 8 nodes; each 8-lane group owns ONE node,
// iterating its (tile-ordered) edge list with a 4-DEEP software pipeline
// (statically-named r0..r3/v0..v3 — no runtime-indexed arrays). Masked FMA
// handles the tail (clamped index, 0/1 weight). Zero cross-lane shuffles.
// Algebra: s = Σ m·v, a1 = Σ m·u·v, a0 = s - a1.
// ---------------------------------------------------------------------------
__global__ __launch_bounds__(256) void pull_agg(
        const int* __restrict__ rowptr, const int* __restrict__ cnt,
        const int2* __restrict__ rec, const unsigned short* __restrict__ featb,
        unsigned short* __restrict__ s01b) {
    int wave_id = (blockIdx.x * 256 + threadIdx.x) >> 6;
    int lane = threadIdx.x & 63;
    int fg = lane & 7;    // 16B chunk (8 bf16) within the 128B row
    int eg = lane >> 3;   // node subgroup 0..7
    int n = wave_id * 8 + eg;
    bool valid = n < N_NODES;
    int start = 0, deg = 0;
    if (valid) { start = rowptr[n]; deg = cnt[n]; }
    int end = start + deg;
    int il  = end - 1;
    const bf16x8* f8 = reinterpret_cast<const bf16x8*>(featb);
    float s[8], a1[8];
#pragma unroll
    for (int k = 0; k < 8; ++k) { s[k] = 0.0f; a1[k] = 0.0f; }

#define LD(IDX, R, V)                                              \
    { int ic = min(IDX, il); R = rec[ic];                          \
      V = f8[((size_t)(unsigned)R.x << 3) + fg]; }
#define MATH(IDX, R, V)                                            \
    { float mk = (IDX < end) ? 1.0f : 0.0f;                        \
      float um = mk * __int_as_float(R.y);                         \
      _Pragma("unroll")                                            \
      for (int t = 0; t < 8; ++t) {                                \
          float vv = bf2f((unsigned short)V[t]);                   \
          s[t]  = fmaf(mk, vv, s[t]);                              \
          a1[t] = fmaf(um, vv, a1[t]);                             \
      } }

    if (deg > 0) {
        int i = start;
        int2 r0, r1, r2, r3; bf16x8 v0, v1, v2, v3;
        LD(i,     r0, v0)
        LD(i + 1, r1, v1)
        LD(i + 2, r2, v2)
        LD(i + 3, r3, v3)
        while (true) {
            int j = i + 4;
            bool more = j < end;
            int2 q0, q1, q2, q3; bf16x8 w0, w1, w2, w3;
            if (more) {           // issue next batch's 4 gathers first
                LD(j,     q0, w0)
                LD(j + 1, q1, w1)
                LD(j + 2, q2, w2)
                LD(j + 3, q3, w3)
            }
            MATH(i,     r0, v0)
            MATH(i + 1, r1, v1)
            MATH(i + 2, r2, v2)
            MATH(i + 3, r3, v3)
            if (!more) break;
            i = j;
            r0 = q0; v0 = w0; r1 = q1; v1 = w1;
            r2 = q2; v2 = w2; r3 = q3; v3 = w3;
        }
    }
#undef LD
#undef MATH

    if (valid) {
        float dinv = 1.0f / fmaxf((float)deg, 1.0f);
        bf16x8 o0, o1;
#pragma unroll
        for (int k = 0; k < 8; ++k) {
            o0[k] = (short)f2bf((s[k] - a1[k]) * dinv);
            o1[k] = (short)f2bf(a1[k] * dinv);
        }
        *reinterpret_cast<bf16x8*>(s01b + (size_t)n * 128 + fg * 8) = o0;
        *reinterpret_cast<bf16x8*>(s01b + (size_t)n * 128 + 64 + fg * 8) = o1;
    }
}

// ---------------------------------------------------------------------------
// MFMA node transform (per block 256 nodes; wave owns 64). K=192 in 6 steps.
// D = Wt-frag x z-frag = C^T: lane holds node = base+(lane&15), channels
// ct*16 + (lane>>4)*4 + reg. ACT=1: ELU->bf16. ACT=2: log_softmax->f32.
// ---------------------------------------------------------------------------
template<int COUT, int CT, int ACT>
__global__ __launch_bounds__(256) void gemm_mfma(
        const unsigned short* __restrict__ s01b,
        const unsigned short* __restrict__ featb,
        const unsigned short* __restrict__ Wt,
        const float* __restrict__ bias, void* __restrict__ outv) {
    int lane = threadIdx.x & 63;
    int wave = threadIdx.x >> 6;
    int l15  = lane & 15;
    int g    = lane >> 4;
    int nodebase = blockIdx.x * 256 + wave * 64;

    f32x4 acc[4][CT];
#pragma unroll
    for (int rt = 0; rt < 4; ++rt)
#pragma unroll
        for (int ct = 0; ct < CT; ++ct) acc[rt][ct] = (f32x4){0.f, 0.f, 0.f, 0.f};

#pragma unroll
    for (int ks = 0; ks < 6; ++ks) {
        int kk = ks * 32 + g * 8;
        bf16x8 zfrag[4];
#pragma unroll
        for (int rt = 0; rt < 4; ++rt) {
            int n = nodebase + rt * 16 + l15;
            if (n >= N_NODES) n = N_NODES - 1;
            const unsigned short* p = (kk < 128)
                ? (s01b + (size_t)n * 128 + kk)
                : (featb + (size_t)n * 64 + (kk - 128));
            zfrag[rt] = *reinterpret_cast<const bf16x8*>(p);
        }
        bf16x8 wfrag[CT];
#pragma unroll
        for (int ct = 0; ct < CT; ++ct)
            wfrag[ct] = *reinterpret_cast<const bf16x8*>(Wt + (size_t)(ct * 16 + l15) * 192 + kk);
#pragma unroll
        for (int rt = 0; rt < 4; ++rt)
#pragma unroll
            for (int ct = 0; ct < CT; ++ct)
                acc[rt][ct] = __builtin_amdgcn_mfma_f32_16x16x32_bf16(
                    wfrag[ct], zfrag[rt], acc[rt][ct], 0, 0, 0);
    }

    f32x4 bv[CT];
#pragma unroll
    for (int ct = 0; ct < CT; ++ct) {
        int base = ct * 16 + g * 4;
        if (base + 4 <= COUT) {
            float4 b = *reinterpret_cast<const float4*>(bias + base);
            bv[ct] = (f32x4){b.x, b.y, b.z, b.w};
        } else {
            bv[ct] = (f32x4){0.f, 0.f, 0.f, 0.f};
        }
    }

    if (ACT == 1) {
        unsigned short* out = (unsigned short*)outv;
#pragma unroll
        for (int rt = 0; rt < 4; ++rt) {
            int n = nodebase + rt * 16 + l15;
            if (n >= N_NODES) continue;
#pragma unroll
            for (int ct = 0; ct < CT; ++ct) {
                f32x4 v = acc[rt][ct] + bv[ct];
                ushort4 o;
                float e;
                e = v[0]; o.x = f2bf(e > 0.f ? e : expm1f(e));
                e = v[1]; o.y = f2bf(e > 0.f ? e : expm1f(e));
                e = v[2]; o.z = f2bf(e > 0.f ? e : expm1f(e));
                e = v[3]; o.w = f2bf(e > 0.f ? e : expm1f(e));
                *reinterpret_cast<ushort4*>(out + (size_t)n * 64 + ct * 16 + g * 4) = o;
            }
        }
    } else {
        float* out = (float*)outv;
#pragma unroll
        for (int rt = 0; rt < 4; ++rt) {
            int n = nodebase + rt * 16 + l15;
            float v[CT * 4];
            float m = -3.4e38f;
#pragma unroll
            for (int ct = 0; ct < CT; ++ct)
#pragma unroll
                for (int r = 0; r < 4; ++r) {
                    int ch = ct * 16 + g * 4 + r;
                    float t = acc[rt][ct][r] + bv[ct][r];
                    v[ct * 4 + r] = t;
                    if (ch < COUT) m = fmaxf(m, t);
                }
            m = fmaxf(m, __shfl_xor(m, 16));
            m = fmaxf(m, __shfl_xor(m, 32));
            float s = 0.0f;
#pragma unroll
            for (int ct = 0; ct < CT; ++ct)
#pragma unroll
                for (int r = 0; r < 4; ++r) {
                    int ch = ct * 16 + g * 4 + r;
                    if (ch < COUT) s += expf(v[ct * 4 + r] - m);
                }
            s += __shfl_xor(s, 16);
            s += __shfl_xor(s, 32);
            float lse = m + logf(s);
            if (n >= N_NODES) continue;
#pragma unroll
            for (int ct = 0; ct < CT; ++ct) {
                int base = ct * 16 + g * 4;
                if (base + 4 <= COUT) {
                    float4 o;
                    o.x = v[ct * 4 + 0] - lse;
                    o.y = v[ct * 4 + 1] - lse;
                    o.z = v[ct * 4 + 2] - lse;
                    o.w = v[ct * 4 + 3] - lse;
                    *reinterpret_cast<float4*>(out + (size_t)n * COUT + base) = o;
                }
            }
        }
    }
}

extern "C" void kernel_launch(void* const* d_in, const int* in_sizes, int n_in,
                              void* d_out, int out_size, void* d_ws, size_t ws_size,
                              hipStream_t stream) {
    const float* x     = (const float*)d_in[0];
    const int*   ei    = (const int*)d_in[1];
    const float* ea    = (const float*)d_in[2];
    const float* W1    = (const float*)d_in[3];
    const float* root1 = (const float*)d_in[4];
    const float* b1    = (const float*)d_in[5];
    const float* W2    = (const float*)d_in[6];
    const float* root2 = (const float*)d_in[7];
    const float* b2    = (const float*)d_in[8];
    float* out = (float*)d_out;

    // workspace layout
    char* p = (char*)d_ws;
    int*   bucket_cur = (int*)p;            p += 512 * 4;
    int2*  binned  = (int2*)p;              p += (size_t)NBUK * BSTRIDE * 8;
    int2*  rec     = (int2*)p;              p += (size_t)N_EDGES * 8;
    int*   rowptr  = (int*)p;               p += (size_t)N_NODES * 4;
    int*   cnt     = (int*)p;               p += (size_t)N_NODES * 4;
    unsigned short* s01b = (unsigned short*)p;  p += (size_t)N_NODES * 128 * 2;
    unsigned short* xb   = (unsigned short*)p;  p += (size_t)N_NODES * 64 * 2;
    unsigned short* hprb = (unsigned short*)p;  p += (size_t)N_NODES * 64 * 2;
    unsigned short* Wt1  = (unsigned short*)p;  p += (size_t)64 * 192 * 2;
    unsigned short* Wt2  = (unsigned short*)p;  p += (size_t)48 * 192 * 2;

    // ---- prep ----
    x2bf16_kernel<<<(N_NODES * 16) / 256, 256, 0, stream>>>(x, xb);
    wt_kernel<<<48, 256, 0, stream>>>(W1, root1, Wt1, 64, 64 * 192);
    wt_kernel<<<36, 256, 0, stream>>>(W2, root2, Wt2, 40, 48 * 192);
    hipMemsetAsync(bucket_cur, 0, 512 * 4, stream);

    // ---- CSR build: 2-phase counting sort, key = (dst, src_tile) ----
    bin_edges<<<NCHA, 256, 0, stream>>>(ei, ea, bucket_cur, binned);
    bucket_sort<<<NBUK, 512, 0, stream>>>(bucket_cur, binned, rec, rowptr, cnt);

    // ---- layer 1 ----  (wave = 8 nodes -> 3125 blocks)
    pull_agg<<<(N_NODES + 31) / 32, 256, 0, stream>>>(rowptr, cnt, rec, xb, s01b);
    gemm_mfma<64, 4, 1><<<NB_SCAN, 256, 0, stream>>>(s01b, xb, Wt1, b1, hprb);

    // ---- layer 2 ----
    pull_agg<<<(N_NODES + 31) / 32, 256, 0, stream>>>(rowptr, cnt, rec, hprb, s01b);
    gemm_mfma<40, 3, 2><<<NB_SCAN, 256, 0, stream>>>(s01b, hprb, Wt2, b2, out);
}